// Round 10
// baseline (286.761 us; speedup 1.0000x reference)
//
#include <hip/hip_runtime.h>

#define NB 8        // batches
#define NC 128      // channels
#define NH 16       // hidden
#define BN_EPS 1e-3f
#define NBLK 2048   // streaming grid
#define HALF (NBLK / 2)
#define RBLK 64     // reduce grid

typedef float v4f __attribute__((ext_vector_type(4)));

__device__ __forceinline__ v4f ntload4(const v4f* p) { return __builtin_nontemporal_load(p); }

// ---------------------------------------------------------------------------
// Prep (1 block): zero sums (kernel, not hipMemsetAsync — memset is not
// replayed inside the captured graph; round-2 bug) and compute the 9 segment
// boundaries of sorted batch_idx. bounds[t] = first row with bidx >= t.
// ---------------------------------------------------------------------------
__global__ __launch_bounds__(256) void k_prep(const int* __restrict__ bidx,
                                              float* __restrict__ sums,
                                              int* __restrict__ bounds,
                                              int N) {
    for (int i = threadIdx.x; i < NB * NC; i += 256) sums[i] = 0.f;
    if (threadIdx.x <= NB) {
        const int t = (int)threadIdx.x;
        int lo = 0, hi = N;
        while (lo < hi) { int m = (lo + hi) >> 1; if (bidx[m] < t) lo = m + 1; else hi = m; }
        bounds[t] = lo;
    }
}

// ---------------------------------------------------------------------------
// Pass 1: segment sum, split-array (blocks < HALF read f3, rest f5), 4x
// unrolled, NONTEMPORAL loads. Round-9 result: nt loads took this kernel
// 162 -> ~65 us (no-allocate reads stop the L3 fill churn that pinned the
// pure-read stream at 3.2 TB/s). KEEP. Merge: per-block partial stores +
// k_reduce (atomic fallback if ws is small).
// ---------------------------------------------------------------------------
__global__ __launch_bounds__(256) void k_segsum(const v4f* __restrict__ f3v,
                                                const v4f* __restrict__ f5v,
                                                const int* __restrict__ bounds,
                                                float* __restrict__ part,   // [NBLK][NB*NC]
                                                float* __restrict__ sums,   // fallback target
                                                int use_part) {
    __shared__ float s[NB][NC];
    __shared__ int sb[NB + 1];
    if (threadIdx.x <= NB) sb[threadIdx.x] = bounds[threadIdx.x];
    for (int i = threadIdx.x; i < NB * NC; i += 256) ((float*)s)[i] = 0.f;
    __syncthreads();

    const v4f* __restrict__ arr = (blockIdx.x < HALF) ? f3v : f5v;
    const int bb = (int)blockIdx.x & (HALF - 1);
    const int lr = threadIdx.x >> 5;          // row-in-block 0..7
    const int cv = threadIdx.x & 31;          // float4 index within the row
    const int base = bb * 8 + lr;
    const int stride = HALF * 8;              // 8192 rows

    for (int seg = 0; seg < NB; ++seg) {
        const int hi = sb[seg + 1];
        v4f acc = (v4f)(0.f);
        int row = sb[seg] + base;
        // 4x unroll: 4 independent nt loads in flight before any use.
        for (; row + 3 * stride < hi; row += 4 * stride) {
            const v4f a0 = ntload4(&arr[(size_t)row * 32 + cv]);
            const v4f a1 = ntload4(&arr[(size_t)(row + stride) * 32 + cv]);
            const v4f a2 = ntload4(&arr[(size_t)(row + 2 * stride) * 32 + cv]);
            const v4f a3 = ntload4(&arr[(size_t)(row + 3 * stride) * 32 + cv]);
            acc += (a0 + a1) + (a2 + a3);
        }
        for (; row < hi; row += stride)
            acc += ntload4(&arr[(size_t)row * 32 + cv]);
        atomicAdd(&s[seg][cv * 4 + 0], acc.x);
        atomicAdd(&s[seg][cv * 4 + 1], acc.y);
        atomicAdd(&s[seg][cv * 4 + 2], acc.z);
        atomicAdd(&s[seg][cv * 4 + 3], acc.w);
    }
    __syncthreads();
    if (use_part) {
        v4f* dst = (v4f*)(part + (size_t)blockIdx.x * (NB * NC));
        if (threadIdx.x < NB * NC / 4) dst[threadIdx.x] = ((const v4f*)s)[threadIdx.x];
    } else {
        for (int i = threadIdx.x; i < NB * NC; i += 256)
            atomicAdd(&sums[i], ((float*)s)[i]);
    }
}

// ---------------------------------------------------------------------------
// Column-sum of the [NBLK][1024] partial matrix into sums[1024]. Coalesced;
// 16 atomics per address total.
// ---------------------------------------------------------------------------
__global__ __launch_bounds__(256) void k_reduce(const float* __restrict__ part,
                                                float* __restrict__ sums) {
    const int t = (int)blockIdx.x * 256 + (int)threadIdx.x;  // 0..16383
    const int col = t & (NB * NC - 1);
    const int chunk = t >> 10;                               // 0..15
    float v = 0.f;
    const int r0 = chunk * (NBLK / 16);
    #pragma unroll 8
    for (int r = r0; r < r0 + NBLK / 16; ++r)
        v += part[(size_t)r * (NB * NC) + col];
    atomicAdd(&sums[col], v);
}

// ---------------------------------------------------------------------------
// Tiny single-block kernel: feat_s = sums/count, squeeze Linear + BN + ReLU,
// excitation, 2-way softmax. att[0..1023]=a3, att[1024..2047]=a5.
// ---------------------------------------------------------------------------
__global__ __launch_bounds__(256) void k_attn(const float* __restrict__ sums,
                                              const int* __restrict__ bounds,
                                              const float* __restrict__ w_sq,   // [NC][NH]
                                              const float* __restrict__ gamma,
                                              const float* __restrict__ beta,
                                              const float* __restrict__ mean,
                                              const float* __restrict__ var,
                                              const float* __restrict__ wex3,   // [NH][NC]
                                              const float* __restrict__ wex5,   // [NH][NC]
                                              float* __restrict__ att) {        // [2][NB][NC]
    __shared__ float fs[NB][NC];
    __shared__ float fz[NB][NH];
    __shared__ float rcnt[NB];

    if (threadIdx.x < NB) {
        const int t = (int)threadIdx.x;
        rcnt[t] = 1.0f / (float)(bounds[t + 1] - bounds[t]);
    }
    __syncthreads();

    for (int i = threadIdx.x; i < NB * NC; i += 256)
        ((float*)fs)[i] = sums[i] * rcnt[i >> 7];
    __syncthreads();

    if (threadIdx.x < NB * NH) {
        const int b = threadIdx.x >> 4;
        const int h = threadIdx.x & 15;
        float z = 0.f;
        #pragma unroll 8
        for (int c = 0; c < NC; ++c) z += fs[b][c] * w_sq[c * NH + h];
        z = (z - mean[h]) * rsqrtf(var[h] + BN_EPS) * gamma[h] + beta[h];
        fz[b][h] = z > 0.f ? z : 0.f;
    }
    __syncthreads();

    for (int i = threadIdx.x; i < NB * NC; i += 256) {
        const int b = i >> 7;
        const int c = i & 127;
        float e3 = 0.f, e5 = 0.f;
        #pragma unroll
        for (int h = 0; h < NH; ++h) {
            const float zz = fz[b][h];
            e3 += zz * wex3[h * NC + c];
            e5 += zz * wex5[h * NC + c];
        }
        const float a3 = 1.f / (1.f + expf(e5 - e3));  // softmax over the 2 branches
        att[i] = a3;
        att[NB * NC + i] = 1.f - a3;
    }
}

// ---------------------------------------------------------------------------
// Pass 2: out = f3*a3[b] + f5*a5[b]; per-segment register weights; 2x unroll.
// PLAIN loads and stores: round-9 showed nontemporal stores regress this
// kernel 130 -> 205 us (stores need the L2/write-combining path). This is
// the round-7 proven shape, ~5.9 TB/s logical.
// ---------------------------------------------------------------------------
__global__ __launch_bounds__(256) void k_combine(const float4* __restrict__ f3v,
                                                 const float4* __restrict__ f5v,
                                                 const int* __restrict__ bounds,
                                                 const float* __restrict__ att,
                                                 float4* __restrict__ outv) {
    __shared__ float4 a3[NB][32];
    __shared__ float4 a5[NB][32];
    __shared__ int sb[NB + 1];
    if (threadIdx.x <= NB) sb[threadIdx.x] = bounds[threadIdx.x];
    const float4* attv = (const float4*)att;
    for (int i = threadIdx.x; i < NB * 32; i += 256) {
        ((float4*)a3)[i] = attv[i];
        ((float4*)a5)[i] = attv[NB * 32 + i];
    }
    __syncthreads();

    const int lr = threadIdx.x >> 5;
    const int cv = threadIdx.x & 31;
    const int base = (int)blockIdx.x * 8 + lr;
    const int stride = NBLK * 8;

    for (int seg = 0; seg < NB; ++seg) {
        const int hi = sb[seg + 1];
        const float4 w3 = a3[seg][cv];
        const float4 w5 = a5[seg][cv];
        int row = sb[seg] + base;
        for (; row + stride < hi; row += 2 * stride) {
            const size_t i0 = (size_t)row * 32 + cv;
            const size_t i1 = (size_t)(row + stride) * 32 + cv;
            const float4 v3a = f3v[i0];
            const float4 v5a = f5v[i0];
            const float4 v3b = f3v[i1];
            const float4 v5b = f5v[i1];
            float4 oa, ob;
            oa.x = v3a.x * w3.x + v5a.x * w5.x;
            oa.y = v3a.y * w3.y + v5a.y * w5.y;
            oa.z = v3a.z * w3.z + v5a.z * w5.z;
            oa.w = v3a.w * w3.w + v5a.w * w5.w;
            ob.x = v3b.x * w3.x + v5b.x * w5.x;
            ob.y = v3b.y * w3.y + v5b.y * w5.y;
            ob.z = v3b.z * w3.z + v5b.z * w5.z;
            ob.w = v3b.w * w3.w + v5b.w * w5.w;
            outv[i0] = oa;
            outv[i1] = ob;
        }
        for (; row < hi; row += stride) {
            const size_t i0 = (size_t)row * 32 + cv;
            const float4 v3 = f3v[i0];
            const float4 v5 = f5v[i0];
            float4 o;
            o.x = v3.x * w3.x + v5.x * w5.x;
            o.y = v3.y * w3.y + v5.y * w5.y;
            o.z = v3.z * w3.z + v5.z * w5.z;
            o.w = v3.w * w3.w + v5.w * w5.w;
            outv[i0] = o;
        }
    }
}

extern "C" void kernel_launch(void* const* d_in, const int* in_sizes, int n_in,
                              void* d_out, int out_size, void* d_ws, size_t ws_size,
                              hipStream_t stream) {
    const float* f3    = (const float*)d_in[0];
    const float* f5    = (const float*)d_in[1];
    const int*   bidx  = (const int*)d_in[2];
    const float* w_sq  = (const float*)d_in[3];
    const float* gamma = (const float*)d_in[4];
    const float* beta  = (const float*)d_in[5];
    const float* mean  = (const float*)d_in[6];
    const float* var   = (const float*)d_in[7];
    const float* wex3  = (const float*)d_in[8];
    const float* wex5  = (const float*)d_in[9];
    float* out = (float*)d_out;

    const int N = in_sizes[2];                  // 500000 rows

    // Workspace layout: part [NBLK][1024] | sums [1024] | att [2048] | bounds.
    const size_t part_bytes = (size_t)NBLK * NB * NC * 4;
    const size_t small_bytes = (size_t)(NB * NC) * 4 + (size_t)(2 * NB * NC) * 4 + 64;
    const int use_part = (ws_size >= part_bytes + small_bytes) ? 1 : 0;

    float* part   = (float*)d_ws;
    float* sums   = part + (use_part ? (size_t)NBLK * NB * NC : 0);
    float* att    = sums + NB * NC;
    int*   bounds = (int*)(att + 2 * NB * NC);

    k_prep<<<1, 256, 0, stream>>>(bidx, sums, bounds, N);
    k_segsum<<<NBLK, 256, 0, stream>>>((const v4f*)f3, (const v4f*)f5, bounds,
                                       part, sums, use_part);
    if (use_part) k_reduce<<<RBLK, 256, 0, stream>>>(part, sums);
    k_attn<<<1, 256, 0, stream>>>(sums, bounds, w_sq, gamma, beta, mean, var, wex3, wex5, att);
    k_combine<<<NBLK, 256, 0, stream>>>((const float4*)f3, (const float4*)f5, bounds, att,
                                        (float4*)out);
}

// Round 11
// 258.264 us; speedup vs baseline: 1.1103x; 1.1103x over previous
//
#include <hip/hip_runtime.h>

#define NB 8        // batches
#define NC 128      // channels
#define NH 16       // hidden
#define BN_EPS 1e-3f
#define NBLK 2048   // streaming grid
#define HALF (NBLK / 2)
#define RBLK 64     // reduce grid

typedef float v4f __attribute__((ext_vector_type(4)));

__device__ __forceinline__ v4f ntload4(const v4f* p) { return __builtin_nontemporal_load(p); }

// ---------------------------------------------------------------------------
// Prep (1 block): zero sums (kernel, not hipMemsetAsync — memset is not
// replayed inside the captured graph; round-2 bug) and compute the 9 segment
// boundaries of sorted batch_idx. bounds[t] = first row with bidx >= t.
// ---------------------------------------------------------------------------
__global__ __launch_bounds__(256) void k_prep(const int* __restrict__ bidx,
                                              float* __restrict__ sums,
                                              int* __restrict__ bounds,
                                              int N) {
    for (int i = threadIdx.x; i < NB * NC; i += 256) sums[i] = 0.f;
    if (threadIdx.x <= NB) {
        const int t = (int)threadIdx.x;
        int lo = 0, hi = N;
        while (lo < hi) { int m = (lo + hi) >> 1; if (bidx[m] < t) lo = m + 1; else hi = m; }
        bounds[t] = lo;
    }
}

// ---------------------------------------------------------------------------
// Pass 1: segment sum, split-array (blocks < HALF read f3, rest f5), 4x
// unrolled, NONTEMPORAL loads. Round-9/10: nt loads run this pure-read pass
// at ~8 TB/s logical (~65-85 us) vs 3.2 TB/s with regular loads (L3
// allocate/fill churn). Merge: per-block partial stores + k_reduce.
// ---------------------------------------------------------------------------
__global__ __launch_bounds__(256) void k_segsum(const v4f* __restrict__ f3v,
                                                const v4f* __restrict__ f5v,
                                                const int* __restrict__ bounds,
                                                float* __restrict__ part,   // [NBLK][NB*NC]
                                                float* __restrict__ sums,   // fallback target
                                                int use_part) {
    __shared__ float s[NB][NC];
    __shared__ int sb[NB + 1];
    if (threadIdx.x <= NB) sb[threadIdx.x] = bounds[threadIdx.x];
    for (int i = threadIdx.x; i < NB * NC; i += 256) ((float*)s)[i] = 0.f;
    __syncthreads();

    const v4f* __restrict__ arr = (blockIdx.x < HALF) ? f3v : f5v;
    const int bb = (int)blockIdx.x & (HALF - 1);
    const int lr = threadIdx.x >> 5;          // row-in-block 0..7
    const int cv = threadIdx.x & 31;          // float4 index within the row
    const int base = bb * 8 + lr;
    const int stride = HALF * 8;              // 8192 rows

    for (int seg = 0; seg < NB; ++seg) {
        const int hi = sb[seg + 1];
        v4f acc = (v4f)(0.f);
        int row = sb[seg] + base;
        // 4x unroll: 4 independent nt loads in flight before any use.
        for (; row + 3 * stride < hi; row += 4 * stride) {
            const v4f a0 = ntload4(&arr[(size_t)row * 32 + cv]);
            const v4f a1 = ntload4(&arr[(size_t)(row + stride) * 32 + cv]);
            const v4f a2 = ntload4(&arr[(size_t)(row + 2 * stride) * 32 + cv]);
            const v4f a3 = ntload4(&arr[(size_t)(row + 3 * stride) * 32 + cv]);
            acc += (a0 + a1) + (a2 + a3);
        }
        for (; row < hi; row += stride)
            acc += ntload4(&arr[(size_t)row * 32 + cv]);
        atomicAdd(&s[seg][cv * 4 + 0], acc.x);
        atomicAdd(&s[seg][cv * 4 + 1], acc.y);
        atomicAdd(&s[seg][cv * 4 + 2], acc.z);
        atomicAdd(&s[seg][cv * 4 + 3], acc.w);
    }
    __syncthreads();
    if (use_part) {
        v4f* dst = (v4f*)(part + (size_t)blockIdx.x * (NB * NC));
        if (threadIdx.x < NB * NC / 4) dst[threadIdx.x] = ((const v4f*)s)[threadIdx.x];
    } else {
        for (int i = threadIdx.x; i < NB * NC; i += 256)
            atomicAdd(&sums[i], ((float*)s)[i]);
    }
}

// ---------------------------------------------------------------------------
// Column-sum of the [NBLK][1024] partial matrix into sums[1024]. Coalesced;
// 16 atomics per address total. part is fresh in L2/L3 -> regular loads.
// ---------------------------------------------------------------------------
__global__ __launch_bounds__(256) void k_reduce(const float* __restrict__ part,
                                                float* __restrict__ sums) {
    const int t = (int)blockIdx.x * 256 + (int)threadIdx.x;  // 0..16383
    const int col = t & (NB * NC - 1);
    const int chunk = t >> 10;                               // 0..15
    float v = 0.f;
    const int r0 = chunk * (NBLK / 16);
    #pragma unroll 8
    for (int r = r0; r < r0 + NBLK / 16; ++r)
        v += part[(size_t)r * (NB * NC) + col];
    atomicAdd(&sums[col], v);
}

// ---------------------------------------------------------------------------
// Tiny single-block kernel: feat_s = sums/count, squeeze Linear + BN + ReLU,
// excitation, 2-way softmax. att[0..1023]=a3, att[1024..2047]=a5.
// ---------------------------------------------------------------------------
__global__ __launch_bounds__(256) void k_attn(const float* __restrict__ sums,
                                              const int* __restrict__ bounds,
                                              const float* __restrict__ w_sq,   // [NC][NH]
                                              const float* __restrict__ gamma,
                                              const float* __restrict__ beta,
                                              const float* __restrict__ mean,
                                              const float* __restrict__ var,
                                              const float* __restrict__ wex3,   // [NH][NC]
                                              const float* __restrict__ wex5,   // [NH][NC]
                                              float* __restrict__ att) {        // [2][NB][NC]
    __shared__ float fs[NB][NC];
    __shared__ float fz[NB][NH];
    __shared__ float rcnt[NB];

    if (threadIdx.x < NB) {
        const int t = (int)threadIdx.x;
        rcnt[t] = 1.0f / (float)(bounds[t + 1] - bounds[t]);
    }
    __syncthreads();

    for (int i = threadIdx.x; i < NB * NC; i += 256)
        ((float*)fs)[i] = sums[i] * rcnt[i >> 7];
    __syncthreads();

    if (threadIdx.x < NB * NH) {
        const int b = threadIdx.x >> 4;
        const int h = threadIdx.x & 15;
        float z = 0.f;
        #pragma unroll 8
        for (int c = 0; c < NC; ++c) z += fs[b][c] * w_sq[c * NH + h];
        z = (z - mean[h]) * rsqrtf(var[h] + BN_EPS) * gamma[h] + beta[h];
        fz[b][h] = z > 0.f ? z : 0.f;
    }
    __syncthreads();

    for (int i = threadIdx.x; i < NB * NC; i += 256) {
        const int b = i >> 7;
        const int c = i & 127;
        float e3 = 0.f, e5 = 0.f;
        #pragma unroll
        for (int h = 0; h < NH; ++h) {
            const float zz = fz[b][h];
            e3 += zz * wex3[h * NC + c];
            e5 += zz * wex5[h * NC + c];
        }
        const float a3 = 1.f / (1.f + expf(e5 - e3));  // softmax over the 2 branches
        att[i] = a3;
        att[NB * NC + i] = 1.f - a3;
    }
}

// ---------------------------------------------------------------------------
// Pass 2: out = f3*a3[b] + f5*a5[b]; per-segment register weights.
// NT LOADS (f3/f5 are single-use here — same pattern that took segsum
// 162->65 us; round-10 showed combine's old 130 us depended on segsum
// having warmed L3, which nt-segsum no longer does) + PLAIN stores
// (nt stores regressed 130->205 in round 9). 4x unroll: 8 nt loads in
// flight to cover HBM latency.
// ---------------------------------------------------------------------------
__global__ __launch_bounds__(256) void k_combine(const v4f* __restrict__ f3v,
                                                 const v4f* __restrict__ f5v,
                                                 const int* __restrict__ bounds,
                                                 const float* __restrict__ att,
                                                 v4f* __restrict__ outv) {
    __shared__ v4f a3[NB][32];
    __shared__ v4f a5[NB][32];
    __shared__ int sb[NB + 1];
    if (threadIdx.x <= NB) sb[threadIdx.x] = bounds[threadIdx.x];
    const v4f* attv = (const v4f*)att;
    for (int i = threadIdx.x; i < NB * 32; i += 256) {
        ((v4f*)a3)[i] = attv[i];
        ((v4f*)a5)[i] = attv[NB * 32 + i];
    }
    __syncthreads();

    const int lr = threadIdx.x >> 5;
    const int cv = threadIdx.x & 31;
    const int base = (int)blockIdx.x * 8 + lr;
    const int stride = NBLK * 8;

    for (int seg = 0; seg < NB; ++seg) {
        const int hi = sb[seg + 1];
        const v4f w3 = a3[seg][cv];
        const v4f w5 = a5[seg][cv];
        int row = sb[seg] + base;
        for (; row + 3 * stride < hi; row += 4 * stride) {
            const size_t i0 = (size_t)row * 32 + cv;
            const size_t i1 = (size_t)(row + stride) * 32 + cv;
            const size_t i2 = (size_t)(row + 2 * stride) * 32 + cv;
            const size_t i3 = (size_t)(row + 3 * stride) * 32 + cv;
            const v4f v3a = ntload4(&f3v[i0]);
            const v4f v5a = ntload4(&f5v[i0]);
            const v4f v3b = ntload4(&f3v[i1]);
            const v4f v5b = ntload4(&f5v[i1]);
            const v4f v3c = ntload4(&f3v[i2]);
            const v4f v5c = ntload4(&f5v[i2]);
            const v4f v3d = ntload4(&f3v[i3]);
            const v4f v5d = ntload4(&f5v[i3]);
            outv[i0] = v3a * w3 + v5a * w5;
            outv[i1] = v3b * w3 + v5b * w5;
            outv[i2] = v3c * w3 + v5c * w5;
            outv[i3] = v3d * w3 + v5d * w5;
        }
        for (; row < hi; row += stride) {
            const size_t i0 = (size_t)row * 32 + cv;
            const v4f v3 = ntload4(&f3v[i0]);
            const v4f v5 = ntload4(&f5v[i0]);
            outv[i0] = v3 * w3 + v5 * w5;
        }
    }
}

extern "C" void kernel_launch(void* const* d_in, const int* in_sizes, int n_in,
                              void* d_out, int out_size, void* d_ws, size_t ws_size,
                              hipStream_t stream) {
    const float* f3    = (const float*)d_in[0];
    const float* f5    = (const float*)d_in[1];
    const int*   bidx  = (const int*)d_in[2];
    const float* w_sq  = (const float*)d_in[3];
    const float* gamma = (const float*)d_in[4];
    const float* beta  = (const float*)d_in[5];
    const float* mean  = (const float*)d_in[6];
    const float* var   = (const float*)d_in[7];
    const float* wex3  = (const float*)d_in[8];
    const float* wex5  = (const float*)d_in[9];
    float* out = (float*)d_out;

    const int N = in_sizes[2];                  // 500000 rows

    // Workspace layout: part [NBLK][1024] | sums [1024] | att [2048] | bounds.
    const size_t part_bytes = (size_t)NBLK * NB * NC * 4;
    const size_t small_bytes = (size_t)(NB * NC) * 4 + (size_t)(2 * NB * NC) * 4 + 64;
    const int use_part = (ws_size >= part_bytes + small_bytes) ? 1 : 0;

    float* part   = (float*)d_ws;
    float* sums   = part + (use_part ? (size_t)NBLK * NB * NC : 0);
    float* att    = sums + NB * NC;
    int*   bounds = (int*)(att + 2 * NB * NC);

    k_prep<<<1, 256, 0, stream>>>(bidx, sums, bounds, N);
    k_segsum<<<NBLK, 256, 0, stream>>>((const v4f*)f3, (const v4f*)f5, bounds,
                                       part, sums, use_part);
    if (use_part) k_reduce<<<RBLK, 256, 0, stream>>>(part, sums);
    k_attn<<<1, 256, 0, stream>>>(sums, bounds, w_sq, gamma, beta, mean, var, wex3, wex5, att);
    k_combine<<<NBLK, 256, 0, stream>>>((const v4f*)f3, (const v4f*)f5, bounds, att,
                                        (v4f*)out);
}